// Round 1
// baseline (662.781 us; speedup 1.0000x reference)
//
#include <hip/hip_runtime.h>
#include <math.h>

// Problem constants
#define D_FEAT 8192
#define T_RES  2048
#define NC4    (D_FEAT/4)     // 2048 float4 columns
#define LORD   16
#define NTHR   256
#define NBLK   512            // k_apply grid: 2 blocks/CU, 4 rows/block
#define ROWS   (T_RES/NBLK)   // 4
#define CPT    (NC4/NTHR)     // 8 float4 per thread (full 8192-wide coverage per block)

// Workspace layout (float offsets). Total ~16.8 MB.
#define OFF_Q    0
#define OFF_WA   (17*D_FEAT)
#define OFF_WB   (OFF_WA + D_FEAT)
#define OFF_U    (OFF_WB + D_FEAT)              // U[k][t] = (R q_k)_t, 16x2048
#define OFF_PART (OFF_U + LORD*T_RES)
#define OFF_SCAL (OFF_PART + NBLK*D_FEAT)

#define SC_FF    0
#define SC_FHF   1
#define SC_NF2   2
#define SC_ALPHA 3    // 16
#define SC_BETA2 19   // 16 (b^2)
#define SC_C     35   // 16 steps x 17 slots
#define SC_COEF  307  // 16
#define SCAL_N   352

__device__ __forceinline__ float blk_reduce(float v, float* lds) {
    #pragma unroll
    for (int o = 32; o > 0; o >>= 1) v += __shfl_down(v, o, 64);
    const int w = threadIdx.x >> 6, l = threadIdx.x & 63;
    if (l == 0) lds[w] = v;
    __syncthreads();
    float s = lds[0] + lds[1] + lds[2] + lds[3];
    __syncthreads();
    return s;
}

__global__ void k_zero(float* __restrict__ scal) {
    for (int i = threadIdx.x; i < SCAL_N; i += blockDim.x) scal[i] = 0.f;
}

// Fused apply_H: one pass over R. Each block owns ROWS rows and the FULL 8192
// columns (32 floats/thread). Per row: u = R[t]·q (block reduce), then
// y_partial -= u * R[t] from registers. Writes per-block partial y; atomics for
// a = q·y = -sum(u^2) and c_raw_k = Q_k·y = -U_k·u (via cached U rows, 8 floats/row).
template<bool INIT>
__global__ __launch_bounds__(NTHR, 1) void k_apply(
    const float* __restrict__ Rm, const float* __restrict__ vin,
    const float* __restrict__ b2ptr, float* __restrict__ Qrow,
    float* __restrict__ Uvec, int j,
    float* __restrict__ partials, float* __restrict__ a_slot,
    float* __restrict__ c_slot, float* __restrict__ ff_slot)
{
    __shared__ float lds[8];
    const int tid = threadIdx.x, bid = blockIdx.x;
    float scale = 1.0f;
    if (!INIT) scale = rsqrtf(fmaxf(*b2ptr, 1e-60f));  // ref: w/max(b,1e-30)
    const float4* v4 = (const float4*)vin;
    float4 q[CPT];
    #pragma unroll
    for (int c = 0; c < CPT; ++c) {
        float4 t = v4[tid + NTHR*c];
        t.x *= scale; t.y *= scale; t.z *= scale; t.w *= scale;
        q[c] = t;
    }
    if (!INIT) {
        if (bid == 0) {  // publish Q[j] once
            float4* Q4 = (float4*)Qrow;
            #pragma unroll
            for (int c = 0; c < CPT; ++c) Q4[tid + NTHR*c] = q[c];
        }
    } else {
        if (bid == 0) {  // f·f for E
            float ffp = 0.f;
            #pragma unroll
            for (int c = 0; c < CPT; ++c)
                ffp += q[c].x*q[c].x + q[c].y*q[c].y + q[c].z*q[c].z + q[c].w*q[c].w;
            ffp = blk_reduce(ffp, lds);
            if (tid == 0) atomicAdd(ff_slot, ffp);
        }
    }
    float4 y[CPT];
    #pragma unroll
    for (int c = 0; c < CPT; ++c) y[c] = make_float4(0.f,0.f,0.f,0.f);

    const float4* R4 = (const float4*)Rm;
    float4 row[CPT], nrow[CPT];
    #pragma unroll
    for (int c = 0; c < CPT; ++c) row[c] = R4[(size_t)bid*NC4 + tid + NTHR*c];
    float a_part = 0.f, cpart = 0.f;
    #pragma unroll
    for (int r = 0; r < ROWS; ++r) {
        const int t = bid + NBLK*r;
        if (r + 1 < ROWS) {  // prefetch next row before the block-reduce stall
            const int tn = bid + NBLK*(r+1);
            #pragma unroll
            for (int c = 0; c < CPT; ++c) nrow[c] = R4[(size_t)tn*NC4 + tid + NTHR*c];
        }
        float s = 0.f;
        #pragma unroll
        for (int c = 0; c < CPT; ++c)
            s += row[c].x*q[c].x + row[c].y*q[c].y + row[c].z*q[c].z + row[c].w*q[c].w;
        const float u = blk_reduce(s, lds);
        if (!INIT) {
            if (tid == 0) Uvec[(size_t)j*T_RES + t] = u;
            if (tid < j)  cpart += Uvec[(size_t)tid*T_RES + t] * u;  // c_raw_k partial
        }
        a_part += u*u;
        #pragma unroll
        for (int c = 0; c < CPT; ++c) {
            y[c].x -= u*row[c].x; y[c].y -= u*row[c].y;
            y[c].z -= u*row[c].z; y[c].w -= u*row[c].w;
        }
        if (r + 1 < ROWS) {
            #pragma unroll
            for (int c = 0; c < CPT; ++c) row[c] = nrow[c];
        }
    }
    float4* p4 = (float4*)partials + (size_t)bid*NC4;
    #pragma unroll
    for (int c = 0; c < CPT; ++c) p4[tid + NTHR*c] = y[c];
    if (!INIT) {
        if (tid == 0) { atomicAdd(a_slot, -a_part); atomicAdd(c_slot + j, -a_part); }
        if (tid < j)    atomicAdd(c_slot + tid, -cpart);
    } else {
        if (tid == 0) atomicAdd(a_slot, -a_part);  // f·Hf = -|Rf|^2
    }
}

// Column-wise reduction of the NBLK partial y vectors; block owns 8 float4 cols.
__device__ __forceinline__ float4 reduce_cols(const float* __restrict__ partials,
                                              int c4, float4* lds4) {
    const int tid = threadIdx.x;
    const int sl = tid >> 3;  // 32 slices x (NBLK/32) partial rows
    const float4* p4 = (const float4*)partials;
    float4 acc = make_float4(0.f,0.f,0.f,0.f);
    #pragma unroll
    for (int i = 0; i < NBLK/32; ++i) {
        float4 t = p4[(size_t)(sl*(NBLK/32) + i)*NC4 + c4];
        acc.x += t.x; acc.y += t.y; acc.z += t.z; acc.w += t.w;
    }
    lds4[tid] = acc;
    __syncthreads();
    #pragma unroll
    for (int step = 16; step >= 1; step >>= 1) {
        if (sl < step) {
            float4 o = lds4[tid + step*8];
            float4 m = lds4[tid];
            m.x += o.x; m.y += o.y; m.z += o.z; m.w += o.w;
            lds4[tid] = m;
        }
        __syncthreads();
    }
    return lds4[tid & 7];
}

// w_final = y - sum_{k<=j} c_raw_k Q_k  (algebraically == ref's a/bprev-subtract
// + reorth, to ~1e-6); beta2[j] = |w_final|^2
__global__ __launch_bounds__(NTHR, 1) void k_update(
    const float* __restrict__ partials, const float* __restrict__ Q, int j,
    const float* __restrict__ cvec, float* __restrict__ wout, float* __restrict__ b2out)
{
    __shared__ float4 lds4[NTHR];
    const int tid = threadIdx.x, bid = blockIdx.x;
    const int c4 = (bid << 3) + (tid & 7);
    float4 y = reduce_cols(partials, c4, lds4);
    if (tid < 8) {
        for (int k = 0; k <= j; ++k) {
            const float ck = cvec[k];
            const float4 qk = ((const float4*)Q)[(size_t)k*NC4 + c4];
            y.x -= ck*qk.x; y.y -= ck*qk.y; y.z -= ck*qk.z; y.w -= ck*qk.w;
        }
        float b2 = y.x*y.x + y.y*y.y + y.z*y.z + y.w*y.w;
        #pragma unroll
        for (int o = 4; o > 0; o >>= 1) b2 += __shfl_down(b2, o, 64);
        if (tid == 0) atomicAdd(b2out, b2);
        ((float4*)wout)[c4] = y;
    }
}

// F = E*f - Hf ; normF2 accumulate ; write F to wA
__global__ __launch_bounds__(NTHR, 1) void k_reduce_init(
    const float* __restrict__ partials, const float* __restrict__ f,
    const float* __restrict__ scal, float* __restrict__ wA, float* __restrict__ nf2out)
{
    __shared__ float4 lds4[NTHR];
    const int tid = threadIdx.x, bid = blockIdx.x;
    const int c4 = (bid << 3) + (tid & 7);
    float4 y = reduce_cols(partials, c4, lds4);
    if (tid < 8) {
        const float E = scal[SC_FHF] / (scal[SC_FF] + 1e-15f);
        const float4 fv = ((const float4*)f)[c4];
        float4 F;
        F.x = E*fv.x - y.x; F.y = E*fv.y - y.y; F.z = E*fv.z - y.z; F.w = E*fv.w - y.w;
        float n2 = F.x*F.x + F.y*F.y + F.z*F.z + F.w*F.w;
        #pragma unroll
        for (int o = 4; o > 0; o >>= 1) n2 += __shfl_down(n2, o, 64);
        if (tid == 0) atomicAdd(nf2out, n2);
        ((float4*)wA)[c4] = F;
    }
}

// coeffs = normF * exp(-tau*T) e0 via fp64 Taylor (||tau*T|| <= ~0.6, H is NSD).
// Lane i holds row i of the 16-vector; tridiag matvec via shuffles.
__global__ void k_exp(float* __restrict__ scal)
{
    const int lane = threadIdx.x;
    double a = 0.0, bl = 0.0;
    if (lane < LORD)     a  = (double)scal[SC_ALPHA + lane];
    if (lane < LORD - 1) bl = sqrt(fmax((double)scal[SC_BETA2 + lane], 0.0));
    double bprev = __shfl_up(bl, 1, 64);
    if (lane == 0) bprev = 0.0;
    if (lane >= LORD) { a = 0.0; bl = 0.0; bprev = 0.0; }
    double v = (lane == 0) ? 1.0 : 0.0;
    double acc = v;
    for (int n = 1; n <= 30; ++n) {
        double vm = __shfl_up(v, 1, 64);   if (lane == 0)          vm = 0.0;
        double vp = __shfl_down(v, 1, 64); if (lane >= LORD - 1)   vp = 0.0;
        const double tv = a*v + bprev*vm + bl*vp;
        v = tv * (-0.08 / (double)n);
        acc += v;
    }
    if (lane < LORD) {
        const float nf = sqrtf(fmaxf(scal[SC_NF2], 0.0f));
        scal[SC_COEF + lane] = (float)acc * nf;
    }
}

// dtheta[p] = (D[p]·direction) / (|D[p]|^2 + 1e-4), direction = sum_l coeffs_l Q_l
__global__ __launch_bounds__(NTHR, 1) void k_final(
    const float* __restrict__ Dm, const float* __restrict__ Q,
    const float* __restrict__ coeffs, float* __restrict__ out)
{
    __shared__ float lds[8];
    __shared__ float cs[LORD];
    const int tid = threadIdx.x, p = blockIdx.x;
    if (tid < LORD) cs[tid] = coeffs[tid];
    __syncthreads();
    const float4* D4 = (const float4*)(Dm + (size_t)p*D_FEAT);
    const float4* Q4 = (const float4*)Q;
    float num = 0.f, den = 0.f;
    #pragma unroll
    for (int c = 0; c < CPT; ++c) {
        const int i4 = tid + NTHR*c;
        const float4 dv = D4[i4];
        float4 dir = make_float4(0.f,0.f,0.f,0.f);
        #pragma unroll
        for (int l = 0; l < LORD; ++l) {
            const float4 qv = Q4[(size_t)l*NC4 + i4];
            const float cl = cs[l];
            dir.x += cl*qv.x; dir.y += cl*qv.y; dir.z += cl*qv.z; dir.w += cl*qv.w;
        }
        num += dv.x*dir.x + dv.y*dir.y + dv.z*dir.z + dv.w*dir.w;
        den += dv.x*dv.x + dv.y*dv.y + dv.z*dv.z + dv.w*dv.w;
    }
    num = blk_reduce(num, lds);
    den = blk_reduce(den, lds);
    if (tid == 0) out[p] = num / (den + 1e-4f);
}

extern "C" void kernel_launch(void* const* d_in, const int* in_sizes, int n_in,
                              void* d_out, int out_size, void* d_ws, size_t ws_size,
                              hipStream_t stream)
{
    (void)in_sizes; (void)n_in; (void)out_size; (void)ws_size;
    const float* f  = (const float*)d_in[0];
    const float* Rm = (const float*)d_in[1];
    const float* Dm = (const float*)d_in[2];
    float* ws   = (float*)d_ws;
    float* Q    = ws + OFF_Q;
    float* wA   = ws + OFF_WA;
    float* wB   = ws + OFF_WB;
    float* U    = ws + OFF_U;
    float* part = ws + OFF_PART;
    float* scal = ws + OFF_SCAL;

    k_zero<<<1, NTHR, 0, stream>>>(scal);
    // Hf = -R^T R f  (+ f·f, f·Hf accumulators)
    k_apply<true><<<NBLK, NTHR, 0, stream>>>(Rm, f, nullptr, nullptr, U, 0, part,
                                             scal + SC_FHF, nullptr, scal + SC_FF);
    k_reduce_init<<<NC4/8, NTHR, 0, stream>>>(part, f, scal, wA, scal + SC_NF2);
    for (int j = 0; j < LORD; ++j) {
        const float* win  = (j & 1) ? wB : wA;
        float*       wout = (j & 1) ? wA : wB;
        const float* b2   = (j == 0) ? (scal + SC_NF2) : (scal + SC_BETA2 + (j - 1));
        k_apply<false><<<NBLK, NTHR, 0, stream>>>(Rm, win, b2, Q + (size_t)j*D_FEAT, U, j,
                                                  part, scal + SC_ALPHA + j,
                                                  scal + SC_C + j*17, nullptr);
        k_update<<<NC4/8, NTHR, 0, stream>>>(part, Q, j, scal + SC_C + j*17, wout,
                                             scal + SC_BETA2 + j);
    }
    k_exp<<<1, 64, 0, stream>>>(scal);
    k_final<<<LORD, NTHR, 0, stream>>>(Dm, Q, scal + SC_COEF, (float*)d_out);
}

// Round 2
// 574.699 us; speedup vs baseline: 1.1533x; 1.1533x over previous
//
#include <hip/hip_runtime.h>
#include <math.h>

// Problem constants
#define D_FEAT 8192
#define T_RES  2048
#define NC4    (D_FEAT/4)     // 2048 float4 columns
#define LORD   16

// k_apply geometry: 256 blocks x 512 threads (8 waves), 8 rows/block, 1 block/CU.
#define NTHR_A 512
#define NBLK_A 256
#define ROWS_A 8
#define CPT_A  (NC4/NTHR_A)   // 4 float4 per thread

// reduction kernels: 256 threads
#define NTHR   256
#define CPT    (NC4/NTHR)     // 8 float4 per thread

// Workspace layout (float offsets). Total ~8.8 MB.
#define OFF_Q    0
#define OFF_WA   (17*D_FEAT)
#define OFF_WB   (OFF_WA + D_FEAT)
#define OFF_U    (OFF_WB + D_FEAT)              // U[k][t] = (R q_k)_t, 16x2048
#define OFF_PART (OFF_U + LORD*T_RES)
#define OFF_SCAL (OFF_PART + NBLK_A*D_FEAT)

#define SC_FF    0
#define SC_FHF   1
#define SC_NF2   2
#define SC_ALPHA 3    // 16
#define SC_BETA2 19   // 16 (b^2)
#define SC_C     35   // 16 steps x 17 slots
#define SC_COEF  307  // 16
#define SCAL_N   352

__device__ __forceinline__ float blk_reduce(float v, float* lds) {
    #pragma unroll
    for (int o = 32; o > 0; o >>= 1) v += __shfl_down(v, o, 64);
    const int w = threadIdx.x >> 6, l = threadIdx.x & 63;
    if (l == 0) lds[w] = v;
    __syncthreads();
    float s = lds[0] + lds[1] + lds[2] + lds[3];
    __syncthreads();
    return s;
}

__global__ void k_zero(float* __restrict__ scal) {
    for (int i = threadIdx.x; i < SCAL_N; i += blockDim.x) scal[i] = 0.f;
}

// Fused apply_H: one pass over R. Block owns ROWS_A contiguous rows and the FULL
// 8192 columns. All 8 row-dots computed up-front from registers, reduced with a
// SINGLE barrier (lane0 LDS scatter + in-wave xor-gather), then 8 rank-1 updates.
// Writes per-block partial y; atomics for a = -sum(u^2) and c_raw_k = -U_k.u.
template<bool INIT>
__global__ __launch_bounds__(NTHR_A, 2) void k_apply(
    const float* __restrict__ Rm, const float* __restrict__ vin,
    const float* __restrict__ b2ptr, float* __restrict__ Qrow,
    float* __restrict__ Uvec, int j,
    float* __restrict__ partials, float* __restrict__ a_slot,
    float* __restrict__ c_slot, float* __restrict__ ff_slot)
{
    __shared__ float lds_red[64];   // [r*8 + wave]
    const int tid = threadIdx.x, bid = blockIdx.x;
    const int wave = tid >> 6, lane = tid & 63;
    float scale = 1.0f;
    if (!INIT) scale = rsqrtf(fmaxf(*b2ptr, 1e-60f));  // ref: w/max(b,1e-30)

    const float4* v4 = (const float4*)vin;
    float4 q[CPT_A];
    #pragma unroll
    for (int c = 0; c < CPT_A; ++c) {
        float4 t = v4[tid + NTHR_A*c];
        t.x *= scale; t.y *= scale; t.z *= scale; t.w *= scale;
        q[c] = t;
    }
    if (!INIT) {
        if (bid == 0) {  // publish Q[j] once
            float4* Q4 = (float4*)Qrow;
            #pragma unroll
            for (int c = 0; c < CPT_A; ++c) Q4[tid + NTHR_A*c] = q[c];
        }
    } else {
        if (bid == 0) {  // f.f for E (per-wave shuffle + atomic)
            float ffp = 0.f;
            #pragma unroll
            for (int c = 0; c < CPT_A; ++c)
                ffp += q[c].x*q[c].x + q[c].y*q[c].y + q[c].z*q[c].z + q[c].w*q[c].w;
            #pragma unroll
            for (int o = 32; o > 0; o >>= 1) ffp += __shfl_down(ffp, o, 64);
            if (lane == 0) atomicAdd(ff_slot, ffp);
        }
    }

    const float4* R4 = (const float4*)Rm;
    const size_t t0 = (size_t)bid * ROWS_A;
    float4 row[ROWS_A][CPT_A];     // 128 VGPRs
    #pragma unroll
    for (int r = 0; r < ROWS_A; ++r)
        #pragma unroll
        for (int c = 0; c < CPT_A; ++c)
            row[r][c] = R4[(t0 + r)*NC4 + tid + NTHR_A*c];

    float s[ROWS_A];
    #pragma unroll
    for (int r = 0; r < ROWS_A; ++r) {
        float acc = 0.f;
        #pragma unroll
        for (int c = 0; c < CPT_A; ++c)
            acc += row[r][c].x*q[c].x + row[r][c].y*q[c].y
                 + row[r][c].z*q[c].z + row[r][c].w*q[c].w;
        s[r] = acc;
    }
    // 8 interleaved wave reductions (ILP across r), single LDS round-trip
    #pragma unroll
    for (int o = 32; o > 0; o >>= 1)
        #pragma unroll
        for (int r = 0; r < ROWS_A; ++r) s[r] += __shfl_down(s[r], o, 64);
    if (lane == 0) {
        #pragma unroll
        for (int r = 0; r < ROWS_A; ++r) lds_red[r*8 + wave] = s[r];
    }
    __syncthreads();
    // each wave: lane (r*8+w) picks lds_red[lane]; xor-sum within groups of 8
    float val = lds_red[lane];
    #pragma unroll
    for (int m = 1; m < 8; m <<= 1) val += __shfl_xor(val, m, 64);
    if (!INIT && wave == 0 && (lane & 7) == 0)
        Uvec[(size_t)j*T_RES + t0 + (lane >> 3)] = val;
    float u[ROWS_A];
    #pragma unroll
    for (int r = 0; r < ROWS_A; ++r) u[r] = __shfl(val, r*8, 64);

    // y = -sum_r u_r * row_r over this block's rows
    float4* p4 = (float4*)partials + (size_t)bid*NC4;
    #pragma unroll
    for (int c = 0; c < CPT_A; ++c) {
        float4 y = make_float4(0.f,0.f,0.f,0.f);
        #pragma unroll
        for (int r = 0; r < ROWS_A; ++r) {
            y.x -= u[r]*row[r][c].x; y.y -= u[r]*row[r][c].y;
            y.z -= u[r]*row[r][c].z; y.w -= u[r]*row[r][c].w;
        }
        p4[tid + NTHR_A*c] = y;
    }

    // scalars
    if (tid == 0) {
        float ap = 0.f;
        #pragma unroll
        for (int r = 0; r < ROWS_A; ++r) ap += u[r]*u[r];
        atomicAdd(a_slot, -ap);
        if (!INIT) atomicAdd(c_slot + j, -ap);
    }
    if (!INIT && wave == 0 && lane < j) {
        float cp = 0.f;
        #pragma unroll
        for (int r = 0; r < ROWS_A; ++r)
            cp += Uvec[(size_t)lane*T_RES + t0 + r] * u[r];
        atomicAdd(c_slot + lane, -cp);
    }
}

// Column-wise reduction of the NBLK_A partial y vectors; block owns 8 float4 cols.
__device__ __forceinline__ float4 reduce_cols(const float* __restrict__ partials,
                                              int c4, float4* lds4) {
    const int tid = threadIdx.x;
    const int sl = tid >> 3;  // 32 slices x (NBLK_A/32) partial rows
    const float4* p4 = (const float4*)partials;
    float4 acc = make_float4(0.f,0.f,0.f,0.f);
    #pragma unroll
    for (int i = 0; i < NBLK_A/32; ++i) {
        float4 t = p4[(size_t)(sl*(NBLK_A/32) + i)*NC4 + c4];
        acc.x += t.x; acc.y += t.y; acc.z += t.z; acc.w += t.w;
    }
    lds4[tid] = acc;
    __syncthreads();
    #pragma unroll
    for (int step = 16; step >= 1; step >>= 1) {
        if (sl < step) {
            float4 o = lds4[tid + step*8];
            float4 m = lds4[tid];
            m.x += o.x; m.y += o.y; m.z += o.z; m.w += o.w;
            lds4[tid] = m;
        }
        __syncthreads();
    }
    return lds4[tid & 7];
}

// w_final = y - sum_{k<=j} c_raw_k Q_k  (algebraically == ref's a/bprev-subtract
// + reorth, to ~1e-6); beta2[j] = |w_final|^2
__global__ __launch_bounds__(NTHR, 1) void k_update(
    const float* __restrict__ partials, const float* __restrict__ Q, int j,
    const float* __restrict__ cvec, float* __restrict__ wout, float* __restrict__ b2out)
{
    __shared__ float4 lds4[NTHR];
    const int tid = threadIdx.x, bid = blockIdx.x;
    const int c4 = (bid << 3) + (tid & 7);
    float4 y = reduce_cols(partials, c4, lds4);
    if (tid < 8) {
        for (int k = 0; k <= j; ++k) {
            const float ck = cvec[k];
            const float4 qk = ((const float4*)Q)[(size_t)k*NC4 + c4];
            y.x -= ck*qk.x; y.y -= ck*qk.y; y.z -= ck*qk.z; y.w -= ck*qk.w;
        }
        float b2 = y.x*y.x + y.y*y.y + y.z*y.z + y.w*y.w;
        #pragma unroll
        for (int o = 4; o > 0; o >>= 1) b2 += __shfl_down(b2, o, 64);
        if (tid == 0) atomicAdd(b2out, b2);
        ((float4*)wout)[c4] = y;
    }
}

// F = E*f - Hf ; normF2 accumulate ; write F to wA
__global__ __launch_bounds__(NTHR, 1) void k_reduce_init(
    const float* __restrict__ partials, const float* __restrict__ f,
    const float* __restrict__ scal, float* __restrict__ wA, float* __restrict__ nf2out)
{
    __shared__ float4 lds4[NTHR];
    const int tid = threadIdx.x, bid = blockIdx.x;
    const int c4 = (bid << 3) + (tid & 7);
    float4 y = reduce_cols(partials, c4, lds4);
    if (tid < 8) {
        const float E = scal[SC_FHF] / (scal[SC_FF] + 1e-15f);
        const float4 fv = ((const float4*)f)[c4];
        float4 F;
        F.x = E*fv.x - y.x; F.y = E*fv.y - y.y; F.z = E*fv.z - y.z; F.w = E*fv.w - y.w;
        float n2 = F.x*F.x + F.y*F.y + F.z*F.z + F.w*F.w;
        #pragma unroll
        for (int o = 4; o > 0; o >>= 1) n2 += __shfl_down(n2, o, 64);
        if (tid == 0) atomicAdd(nf2out, n2);
        ((float4*)wA)[c4] = F;
    }
}

// coeffs = normF * exp(-tau*T) e0 via fp64 Taylor (||tau*T|| <= ~0.6, H is NSD).
// Lane i holds row i of the 16-vector; tridiag matvec via shuffles.
__global__ void k_exp(float* __restrict__ scal)
{
    const int lane = threadIdx.x;
    double a = 0.0, bl = 0.0;
    if (lane < LORD)     a  = (double)scal[SC_ALPHA + lane];
    if (lane < LORD - 1) bl = sqrt(fmax((double)scal[SC_BETA2 + lane], 0.0));
    double bprev = __shfl_up(bl, 1, 64);
    if (lane == 0) bprev = 0.0;
    if (lane >= LORD) { a = 0.0; bl = 0.0; bprev = 0.0; }
    double v = (lane == 0) ? 1.0 : 0.0;
    double acc = v;
    for (int n = 1; n <= 30; ++n) {
        double vm = __shfl_up(v, 1, 64);   if (lane == 0)          vm = 0.0;
        double vp = __shfl_down(v, 1, 64); if (lane >= LORD - 1)   vp = 0.0;
        const double tv = a*v + bprev*vm + bl*vp;
        v = tv * (-0.08 / (double)n);
        acc += v;
    }
    if (lane < LORD) {
        const float nf = sqrtf(fmaxf(scal[SC_NF2], 0.0f));
        scal[SC_COEF + lane] = (float)acc * nf;
    }
}

// dtheta[p] = (D[p].direction) / (|D[p]|^2 + 1e-4), direction = sum_l coeffs_l Q_l
__global__ __launch_bounds__(NTHR, 1) void k_final(
    const float* __restrict__ Dm, const float* __restrict__ Q,
    const float* __restrict__ coeffs, float* __restrict__ out)
{
    __shared__ float lds[8];
    __shared__ float cs[LORD];
    const int tid = threadIdx.x, p = blockIdx.x;
    if (tid < LORD) cs[tid] = coeffs[tid];
    __syncthreads();
    const float4* D4 = (const float4*)(Dm + (size_t)p*D_FEAT);
    const float4* Q4 = (const float4*)Q;
    float num = 0.f, den = 0.f;
    #pragma unroll
    for (int c = 0; c < CPT; ++c) {
        const int i4 = tid + NTHR*c;
        const float4 dv = D4[i4];
        float4 dir = make_float4(0.f,0.f,0.f,0.f);
        #pragma unroll
        for (int l = 0; l < LORD; ++l) {
            const float4 qv = Q4[(size_t)l*NC4 + i4];
            const float cl = cs[l];
            dir.x += cl*qv.x; dir.y += cl*qv.y; dir.z += cl*qv.z; dir.w += cl*qv.w;
        }
        num += dv.x*dir.x + dv.y*dir.y + dv.z*dir.z + dv.w*dir.w;
        den += dv.x*dv.x + dv.y*dv.y + dv.z*dv.z + dv.w*dv.w;
    }
    num = blk_reduce(num, lds);
    den = blk_reduce(den, lds);
    if (tid == 0) out[p] = num / (den + 1e-4f);
}

extern "C" void kernel_launch(void* const* d_in, const int* in_sizes, int n_in,
                              void* d_out, int out_size, void* d_ws, size_t ws_size,
                              hipStream_t stream)
{
    (void)in_sizes; (void)n_in; (void)out_size; (void)ws_size;
    const float* f  = (const float*)d_in[0];
    const float* Rm = (const float*)d_in[1];
    const float* Dm = (const float*)d_in[2];
    float* ws   = (float*)d_ws;
    float* Q    = ws + OFF_Q;
    float* wA   = ws + OFF_WA;
    float* wB   = ws + OFF_WB;
    float* U    = ws + OFF_U;
    float* part = ws + OFF_PART;
    float* scal = ws + OFF_SCAL;

    k_zero<<<1, NTHR, 0, stream>>>(scal);
    // Hf = -R^T R f  (+ f.f, f.Hf accumulators)
    k_apply<true><<<NBLK_A, NTHR_A, 0, stream>>>(Rm, f, nullptr, nullptr, U, 0, part,
                                                 scal + SC_FHF, nullptr, scal + SC_FF);
    k_reduce_init<<<NC4/8, NTHR, 0, stream>>>(part, f, scal, wA, scal + SC_NF2);
    for (int j = 0; j < LORD; ++j) {
        const float* win  = (j & 1) ? wB : wA;
        float*       wout = (j & 1) ? wA : wB;
        const float* b2   = (j == 0) ? (scal + SC_NF2) : (scal + SC_BETA2 + (j - 1));
        k_apply<false><<<NBLK_A, NTHR_A, 0, stream>>>(Rm, win, b2, Q + (size_t)j*D_FEAT, U, j,
                                                      part, scal + SC_ALPHA + j,
                                                      scal + SC_C + j*17, nullptr);
        k_update<<<NC4/8, NTHR, 0, stream>>>(part, Q, j, scal + SC_C + j*17, wout,
                                             scal + SC_BETA2 + j);
    }
    k_exp<<<1, 64, 0, stream>>>(scal);
    k_final<<<LORD, NTHR, 0, stream>>>(Dm, Q, scal + SC_COEF, (float*)d_out);
}